// Round 4
// baseline (83.305 us; speedup 1.0000x reference)
//
#include <hip/hip_runtime.h>

#define W 144
#define PLANE (144 * 144)
#define VOL (144 * 144 * 144)
#define NB 2
#define NFIELD 4   // {sum_p, sum_t, sum_pt, sum_(p^2+t^2)}
#define WIN 11
#define PAD 5
#define YCHUNKS 4
#define YC (W / YCHUNKS)
#define XSEG 3
#define XW 48      // x outputs per wave
#define ZCHUNKS 3
#define ZCHUNK (W / ZCHUNKS)
#define NCELL 256
#define WPB 4      // waves per block

// K12: fused x+y pass, wave-autonomous (no barriers).
// Each wave owns (b, z, y-chunk, x-segment of 48). Lane l stages input at
// x_in = xs*48 - 5 + l into a PRIVATE per-wave LDS line (within-wave
// write->read ordering via lgkmcnt, no __syncthreads). Output lane j<48
// computes the 11-tap x-window from lanes j..j+10, then an 11-deep
// statically-indexed ring gives the y running window. One-row register
// prefetch hides the global-load latency under the tap compute.
__global__ __launch_bounds__(WPB * 64) void
k12_xypass(const float* __restrict__ pred, const float* __restrict__ targ,
           float* __restrict__ ws, double* __restrict__ accL1) {
    const int tid = threadIdx.x;
    const int l = tid & 63;
    const int wid = tid >> 6;
    int wg = blockIdx.x * WPB + wid;
    const int xs = wg % XSEG; wg /= XSEG;
    const int yc = wg % YCHUNKS; wg /= YCHUNKS;
    const int z = wg % W; wg /= W;
    const int b = wg;
    const int y0 = yc * YC;

    const int x_in = xs * XW - PAD + l;  // this lane's staged input x
    const bool vload = (l < XW + 2 * PAD) && (x_in >= 0) && (x_in < W);
    const int xg = (x_in < 0) ? 0 : ((x_in >= W) ? (W - 1) : x_in);
    const size_t base = (size_t)b * VOL + (size_t)z * PLANE;

    __shared__ float sp[WPB][76];
    __shared__ float st[WPB][76];
    float* SP = sp[wid];
    float* ST = st[wid];

    float ring[NFIELD][WIN];
    float s4[NFIELD];
#pragma unroll
    for (int f = 0; f < NFIELD; ++f) {
        s4[f] = 0.f;
#pragma unroll
        for (int k = 0; k < WIN; ++k) ring[f][k] = 0.f;
    }
    float l1 = 0.f;

    const int yl_start = (y0 >= PAD) ? (y0 - PAD) : 0;
    const int yl_end = y0 + YC + PAD;  // exclusive
    const int outx = xs * XW + l;      // output x for lanes l < XW

    // prefetch row yl_start
    float pn = 0.f, tn = 0.f;
    if (vload && yl_start < W) {
        pn = pred[base + yl_start * W + xg];
        tn = targ[base + yl_start * W + xg];
    }

    for (int c = 0; c < 5; ++c) {
#pragma unroll
        for (int u = 0; u < WIN; ++u) {
            const int i = c * WIN + u;
            const int yl = yl_start + i;
            if (yl < yl_end) {  // wave-uniform guard
                const float p = pn, t = tn;
                // prefetch next row
                pn = 0.f; tn = 0.f;
                const int yn = yl + 1;
                if (vload && yn < yl_end && yn < W) {
                    pn = pred[base + yn * W + xg];
                    tn = targ[base + yn * W + xg];
                }
                SP[l] = p;
                ST[l] = t;
                // L1 on owned voxels: input lanes l in [PAD, PAD+XW), owned rows
                if (yl >= y0 && yl < y0 + YC && l >= PAD && l < PAD + XW)
                    l1 += fabsf(p - t);

                float sx0 = 0.f, sx1 = 0.f, sx2 = 0.f, sx3 = 0.f;
#pragma unroll
                for (int k = 0; k < WIN; ++k) {
                    const float pj = SP[l + k];
                    const float tj = ST[l + k];
                    sx0 += pj;
                    sx1 += tj;
                    sx2 = fmaf(pj, tj, sx2);
                    sx3 = fmaf(pj, pj, sx3);
                    sx3 = fmaf(tj, tj, sx3);
                }
                s4[0] += sx0 - ring[0][u]; ring[0][u] = sx0;
                s4[1] += sx1 - ring[1][u]; ring[1][u] = sx1;
                s4[2] += sx2 - ring[2][u]; ring[2][u] = sx2;
                s4[3] += sx3 - ring[3][u]; ring[3][u] = sx3;

                const int y_out = yl - PAD;
                if (y_out >= y0 && l < XW) {
                    const size_t o = (size_t)z * PLANE + (size_t)y_out * W + outx;
                    ws[(size_t)(0 * NB + b) * VOL + o] = s4[0];
                    ws[(size_t)(1 * NB + b) * VOL + o] = s4[1];
                    ws[(size_t)(2 * NB + b) * VOL + o] = s4[2];
                    ws[(size_t)(3 * NB + b) * VOL + o] = s4[3];
                }
            }
        }
    }

    // wave-level reduction of l1, one atomic per wave
    l1 += __shfl_xor(l1, 32);
    l1 += __shfl_xor(l1, 16);
    l1 += __shfl_xor(l1, 8);
    l1 += __shfl_xor(l1, 4);
    l1 += __shfl_xor(l1, 2);
    l1 += __shfl_xor(l1, 1);
    if (l == 0) atomicAdd(&accL1[(blockIdx.x * WPB + wid) & (NCELL - 1)], (double)l1);
}

// K3: z-window running sum (static ring, unrolled) over 4 fields + SSIM + reduce.
__global__ void k3_zpass(const float* __restrict__ ws, double* __restrict__ accS) {
    const int x = threadIdx.x;
    int bid = blockIdx.x;
    const int c = bid % ZCHUNKS; bid /= ZCHUNKS;
    const int y = bid % W; bid /= W;
    const int b = bid;
    const int zstart = c * ZCHUNK;

    const float* F0 = ws + (size_t)(0 * NB + b) * VOL + y * W + x;
    const float* F1 = ws + (size_t)(1 * NB + b) * VOL + y * W + x;
    const float* F2 = ws + (size_t)(2 * NB + b) * VOL + y * W + x;
    const float* F3 = ws + (size_t)(3 * NB + b) * VOL + y * W + x;

    float ring[NFIELD][WIN];
    float sm[NFIELD];
#pragma unroll
    for (int f = 0; f < NFIELD; ++f) {
        sm[f] = 0.f;
#pragma unroll
        for (int k = 0; k < WIN; ++k) ring[f][k] = 0.f;
    }

    const float inv = 1.0f / 1331.0f;
    const float C1 = 0.01f * 0.01f;
    const float C2 = 0.03f * 0.03f;
    float ssim_acc = 0.f;

    const int NSTEP = ZCHUNK + 2 * PAD;  // 58
    for (int cc = 0; cc < 6; ++cc) {
#pragma unroll
        for (int u = 0; u < WIN; ++u) {
            const int i = cc * WIN + u;
            if (i < NSTEP) {
                const int zl = zstart - PAD + i;
                const bool inb = (zl >= 0) && (zl < W);
                const int zoff = zl * PLANE;
                const float v0 = inb ? F0[zoff] : 0.f;
                const float v1 = inb ? F1[zoff] : 0.f;
                const float v2 = inb ? F2[zoff] : 0.f;
                const float v3 = inb ? F3[zoff] : 0.f;
                sm[0] += v0 - ring[0][u]; ring[0][u] = v0;
                sm[1] += v1 - ring[1][u]; ring[1][u] = v1;
                sm[2] += v2 - ring[2][u]; ring[2][u] = v2;
                sm[3] += v3 - ring[3][u]; ring[3][u] = v3;
                if (i >= 2 * PAD) {
                    const float mu_p = sm[0] * inv;
                    const float mu_t = sm[1] * inv;
                    const float ept = sm[2] * inv;
                    const float esq = sm[3] * inv;
                    const float mupt = mu_p * mu_t;
                    const float musq = mu_p * mu_p + mu_t * mu_t;
                    const float sig_pt = ept - mupt;
                    const float sigsum = esq - musq;
                    const float num = (2.f * mupt + C1) * (2.f * sig_pt + C2);
                    const float den = (musq + C1) * (sigsum + C2);
                    ssim_acc += num / den;
                }
            }
        }
    }

    __shared__ float red[W];
    {
        const int x2 = threadIdx.x;
        red[x2] = ssim_acc;
        __syncthreads();
        if (x2 < 16) {
            float s2 = 0.f;
#pragma unroll
            for (int k = 0; k < 9; ++k) s2 += red[x2 + 16 * k];
            s2 += __shfl_down(s2, 8);
            s2 += __shfl_down(s2, 4);
            s2 += __shfl_down(s2, 2);
            s2 += __shfl_down(s2, 1);
            if (x2 == 0) atomicAdd(&accS[blockIdx.x & (NCELL - 1)], (double)s2);
        }
    }
}

// K4: reduce the 2x256 cells, write the 3 outputs.
__global__ void k4_final(const double* __restrict__ accL1, const double* __restrict__ accS,
                         float* __restrict__ out) {
    const int x = threadIdx.x;
    __shared__ double r1[NCELL];
    __shared__ double r2[NCELL];
    r1[x] = accL1[x];
    r2[x] = accS[x];
    __syncthreads();
    for (int s = NCELL / 2; s > 0; s >>= 1) {
        if (x < s) {
            r1[x] += r1[x + s];
            r2[x] += r2[x + s];
        }
        __syncthreads();
    }
    if (x == 0) {
        const double n = (double)NB * (double)VOL;
        const double l1 = r1[0] / n;
        const double ssim_loss = 1.0 - r2[0] / n;
        const double total = l1 + 0.5 * ssim_loss;
        out[0] = (float)total;
        out[1] = (float)l1;
        out[2] = (float)ssim_loss;
    }
}

extern "C" void kernel_launch(void* const* d_in, const int* in_sizes, int n_in,
                              void* d_out, int out_size, void* d_ws, size_t ws_size,
                              hipStream_t stream) {
    const float* pred = (const float*)d_in[0];
    const float* targ = (const float*)d_in[1];
    float* out = (float*)d_out;
    float* ws = (float*)d_ws;
    double* accL1 = (double*)((char*)d_ws + (size_t)NFIELD * NB * VOL * sizeof(float));
    double* accS = accL1 + NCELL;

    hipMemsetAsync(accL1, 0, 2 * NCELL * sizeof(double), stream);
    const int nwaves = NB * W * YCHUNKS * XSEG;  // 3456
    k12_xypass<<<nwaves / WPB, WPB * 64, 0, stream>>>(pred, targ, ws, accL1);
    k3_zpass<<<NB * W * ZCHUNKS, W, 0, stream>>>(ws, accS);
    k4_final<<<1, NCELL, 0, stream>>>(accL1, accS, out);
}